// Round 12
// baseline (265.664 us; speedup 1.0000x reference)
//
#include <hip/hip_runtime.h>
#include <hip/hip_bf16.h>

// ---------------- problem constants ----------------
#define QSCALE   0.08838834764831845f               // 1/sqrt(128)
#define QKSCALE  0.1275174468755322f                // QSCALE * log2(e)

typedef __attribute__((ext_vector_type(8))) short bh8;   // 8 bf16 (4 VGPRs)
typedef __attribute__((ext_vector_type(4))) float fx4;   // 4 fp32
typedef __attribute__((ext_vector_type(4))) short sh4;

typedef const __attribute__((address_space(1))) unsigned GAu;
typedef __attribute__((address_space(3))) unsigned LAu;

__device__ __forceinline__ short f2bf(float f) {
    unsigned u = __float_as_uint(f);
    unsigned r = u + 0x7fffu + ((u >> 16) & 1u);   // RNE
    return (short)(r >> 16);
}

__device__ __forceinline__ unsigned pk_bf16(float x, float y) {
    union { __hip_bfloat162 h; unsigned u; } cv;
    cv.h = __float22bfloat162_rn(float2{x, y});    // x -> low short, y -> high short
    return cv.u;
}

// ---------------- fused prep: X cvt + 3 weight transposes in ONE launch (R11) ----------------
//   blocks [0,8192)      : cvt X fp32 -> bf16 (1 float4/thread)
//   blocks [8192,12288)  : transpose Wq [2048][2048] -> WqT bf16
//   blocks [12288,13312) : transpose Wk [2048][512]  -> WkT bf16
//   blocks [13312,14336) : transpose Wv [2048][512]  -> WvT bf16
__global__ __launch_bounds__(256) void prep_all(
    const float* __restrict__ x,  short* __restrict__ xo,
    const float* __restrict__ wq, short* __restrict__ wqt,
    const float* __restrict__ wk, short* __restrict__ wkt,
    const float* __restrict__ wv, short* __restrict__ wvt) {
    __shared__ float tile[32][33];
    const int bid = blockIdx.x;

    if (bid < 8192) {
        int i = bid * 256 + threadIdx.x;
        float4 v = ((const float4*)x)[i];
        sh4 s;
        s.x = f2bf(v.x); s.y = f2bf(v.y); s.z = f2bf(v.z); s.w = f2bf(v.w);
        ((sh4*)xo)[i] = s;
        return;
    }

    const float* w; short* wt; int K, N, nb, kb;
    int t = bid - 8192;
    if (t < 4096)      { w = wq; wt = wqt; K = 2048; N = 2048; nb = t & 63; kb = t >> 6; }
    else if (t < 5120) { w = wk; wt = wkt; K = 2048; N = 512;  t -= 4096; nb = t & 15; kb = t >> 4; }
    else               { w = wv; wt = wvt; K = 2048; N = 512;  t -= 5120; nb = t & 15; kb = t >> 4; }

    int tx = threadIdx.x & 31, ty = threadIdx.x >> 5;
#pragma unroll
    for (int j = 0; j < 4; ++j) {
        int k = kb * 32 + ty + j * 8;
        tile[ty + j * 8][tx] = w[(size_t)k * N + nb * 32 + tx];
    }
    __syncthreads();
#pragma unroll
    for (int j = 0; j < 4; ++j) {
        int n = nb * 32 + ty + j * 8;
        wt[(size_t)n * K + kb * 32 + tx] = f2bf(tile[tx][ty + j * 8]);
    }
}

// ---------------- fused QKV projection GEMM (static double-buffer, R4 form) ----------------
// C[4096 x 3072]: n-tiles 0..15 -> Q, 16..19 -> K, 20..23 -> V
// Verified at ~93us (R9/R11). R10's counted-vmcnt port REGRESSED here
// (4-wave lockstep: extra barriers cost more than the drain they removed) --
// keep the R4 schedule: static-named dbuf, stage(next) before compute(cur),
// one __syncthreads per tile.
// R7 Kpk packing (for swapped-QK attn): frag (b,g,kt32,nti,ks): key u = s&31
// maps to group nti=(u>>2)&1, frag row fl16=(u>>3)*4+(u&3); lane=qd*16+fl16,
// j<8 holds K[key][ks*32+qd*8+j]. Swapped QK^T then lands lane-exact as the
// PV A-fragment. Vpk unchanged.
__global__ __launch_bounds__(256) void proj_gemm(
    const short* __restrict__ X,     // [4096][2048] bf16
    const short* __restrict__ WqT,   // [2048][2048] bf16 (N-major)
    const short* __restrict__ WkT,   // [512][2048]
    const short* __restrict__ WvT,   // [512][2048]
    const float* __restrict__ bq, const float* __restrict__ bk,
    const float* __restrict__ bv,
    short* __restrict__ Qb, short* __restrict__ Kpk, short* __restrict__ Vpk) {
    __shared__ short As0[128 * 32];
    __shared__ short As1[128 * 32];
    __shared__ short Bs0[128 * 32];
    __shared__ short Bs1[128 * 32];

    const int tid = threadIdx.x;
    const int bm = blockIdx.x;      // 0..31
    const int ntg = blockIdx.y;     // 0..23

    const short* Wm; const float* bias; int col0, kind;
    if (ntg < 16)      { Wm = WqT; bias = bq; col0 = ntg * 128;        kind = 0; }
    else if (ntg < 20) { Wm = WkT; bias = bk; col0 = (ntg - 16) * 128; kind = 1; }
    else               { Wm = WvT; bias = bv; col0 = (ntg - 20) * 128; kind = 2; }

    const int w = tid >> 6, lane = tid & 63, quad = lane >> 4, l16 = lane & 15;

    fx4 acc[2][8];
#pragma unroll
    for (int i = 0; i < 2; ++i)
#pragma unroll
        for (int j = 0; j < 8; ++j) acc[i][j] = fx4{0.f, 0.f, 0.f, 0.f};

    const int srow = w * 16 + (lane >> 2);
    const int scol = (((lane & 3) ^ ((lane >> 2) & 3)) * 8);
    const short* Ag = X + (size_t)(bm * 128 + srow) * 2048 + scol;
    const short* Bg = Wm + (size_t)(col0 + srow) * 2048 + scol;
    const int stoff = w * 512;      // per-wave LDS staging offset

    const int fchunk = (quad ^ (l16 & 3)) * 8;
    const int aoff0 = (w * 32 + l16) * 32 + fchunk;       // A rows w*32+l16
    const int aoff1 = aoff0 + 512;                        // A rows w*32+16+l16
    const int boff  = l16 * 32 + fchunk;                  // B row nt*16+l16 base

    // hoisted read pointers (all compile-time offsets from static arrays)
    const short* pA00 = As0 + aoff0;  const short* pA01 = As0 + aoff1;
    const short* pA10 = As1 + aoff0;  const short* pA11 = As1 + aoff1;
    const short* pB0  = Bs0 + boff;   const short* pB1  = Bs1 + boff;

#define PG_STAGE(AsD, BsD, ktile)                                               \
    do {                                                                        \
        const int k0_ = (ktile) * 32;                                           \
        _Pragma("unroll")                                                       \
        for (int j = 0; j < 2; ++j) {                                           \
            __builtin_amdgcn_global_load_lds(                                   \
                (GAu*)(Ag + (size_t)(j * 64) * 2048 + k0_),                     \
                (LAu*)(AsD + stoff + j * 2048), 16, 0, 0);                      \
            __builtin_amdgcn_global_load_lds(                                   \
                (GAu*)(Bg + (size_t)(j * 64) * 2048 + k0_),                     \
                (LAu*)(BsD + stoff + j * 2048), 16, 0, 0);                      \
        }                                                                       \
    } while (0)

#define PG_COMPUTE(pA0_, pA1_, pB_)                                             \
    do {                                                                        \
        bh8 af0 = *(const bh8*)(pA0_);                                          \
        bh8 af1 = *(const bh8*)(pA1_);                                          \
        _Pragma("unroll")                                                       \
        for (int nt = 0; nt < 8; ++nt) {                                        \
            bh8 bf = *(const bh8*)((pB_) + nt * 512);                           \
            acc[0][nt] = __builtin_amdgcn_mfma_f32_16x16x32_bf16(af0, bf, acc[0][nt], 0, 0, 0); \
            acc[1][nt] = __builtin_amdgcn_mfma_f32_16x16x32_bf16(af1, bf, acc[1][nt], 0, 0, 0); \
        }                                                                       \
    } while (0)

    // ---- prologue: stage k-tile 0 into buffer 0 ----
    PG_STAGE(As0, Bs0, 0);
    __syncthreads();   // one exposed drain, prologue only

    for (int kt = 0; kt < 64; kt += 2) {
        // body A: stage odd tile kt+1 into buf1; compute even tile kt from buf0
        PG_STAGE(As1, Bs1, kt + 1);
        PG_COMPUTE(pA00, pA01, pB0);
        __syncthreads();   // drains stage(kt+1); fences buf0 reuse below

        // body B: stage even tile kt+2 into buf0; compute odd tile kt+1 from buf1
        if (kt < 62) PG_STAGE(As0, Bs0, kt + 2);
        PG_COMPUTE(pA10, pA11, pB1);
        __syncthreads();   // drains stage(kt+2); fences buf1 reuse next iter
    }
#undef PG_STAGE
#undef PG_COMPUTE

    // epilogue: row = bm*128 + w*32 + mt*16 + quad*4 + r ; col = col0 + nt*16 + l16
#pragma unroll
    for (int mt = 0; mt < 2; ++mt) {
        int srow2 = bm * 128 + w * 32 + mt * 16 + quad * 4;
#pragma unroll
        for (int nt = 0; nt < 8; ++nt) {
            int c = col0 + nt * 16 + l16;
            float bval = bias[c];
#pragma unroll
            for (int r = 0; r < 4; ++r) {
                int sg = srow2 + r;
                int b = sg >> 11, s = sg & 2047;
                float v = acc[mt][nt][r] + bval;
                int hd = c & 127;
                if (kind == 0) {
                    v *= QKSCALE;  // fold 1/sqrt(d)*log2(e) into Q
                    int h = c >> 7;
                    Qb[(((size_t)(b * 16 + h) * 2048 + s) << 7) + hd] = f2bf(v);
                } else if (kind == 1) {
                    // R7 interleaved packing for swapped-QK (see attn)
                    int g = c >> 7;
                    int kt32 = s >> 5, u = s & 31;
                    int nti = (u >> 2) & 1, fl16 = (u >> 3) * 4 + (u & 3);
                    int ks = hd >> 5, qd = (hd >> 3) & 3, j = hd & 7;
                    size_t frag = (((size_t)(b * 4 + g) * 64 + kt32) * 8 + nti * 4 + ks);
                    Kpk[frag * 512 + (qd * 16 + fl16) * 8 + j] = f2bf(v);
                } else {
                    int g = c >> 7;
                    int ktt = s >> 6, tl = s & 63;
                    int ts = tl >> 5, qd = (tl >> 3) & 3, j = tl & 7;
                    int fnt = hd >> 4, fl16 = hd & 15;
                    size_t frag = (((size_t)(b * 4 + g) * 32 + ktt) * 16 + fnt * 2 + ts);
                    Vpk[frag * 512 + (qd * 16 + fl16) * 8 + j] = f2bf(v);
                }
            }
        }
    }
}

// ---------------- flash attention: zero-LDS, zero-barrier, L2-direct (R12) ----------------
// R11 counters: attn ~90us with no pipe above ~31% -> latency/sync-bound.
// The 2 waves' only shared state was the LDS K/V tile; with XCD-local KV
// (bid&7 mapping) the whole KV set is L2-resident, and L2-direct register
// loads cost 1024blk x 64tile x 32KB = 2.1GB / ~80us ~= 3.4 TB/s per XCD
// (under the ~4.3 ceiling). So: NO LDS, NO barriers, NO waitcnt asm --
// correctness is pure per-wave dataflow; the compiler inserts exact counted
// vmcnt (G7). Pipeline: static register K double-buffer kA/kB (R4 lesson
// applied to registers -- manual x2 unroll, no runtime index, no copies);
// V loads issued at the top of each half so L2 latency hides under the QK
// cluster; next-tile K issued before compute so it hides under QK+SM+PV.
// VGPR ~230 < 256 -> still 2 waves/SIMD. setprio kept (m191: helps
// unsynchronized attn waves).
__global__ __launch_bounds__(128, 2) void attn(
    const short* __restrict__ Qb,   // [B][HQ][S][128] bf16, pre-scaled by QKSCALE
    const short* __restrict__ Kpk,  // packed A-frags (interleaved keys)
    const short* __restrict__ Vpk,  // packed B-frags
    float* __restrict__ out) {      // [B][S][D] fp32
    const int bid = blockIdx.x;
    const int gb = bid & 7;              // XCD selector = (b*4+g)
    const int rep = (bid >> 3) & 3;
    const int qt = bid >> 5;             // 0..31
    const int b = gb >> 2, g = gb & 3;
    const int h = rep * 4 + g;
    const int tid = threadIdx.x, w = tid >> 6, lane = tid & 63;
    const int quad = lane >> 4, l16 = lane & 15;

    // Q fragments: wave w owns rows qt*64 + w*32 + rg*16 + l16 (as B operand)
    bh8 qf[2][4];
#pragma unroll
    for (int rg = 0; rg < 2; ++rg) {
        int s = qt * 64 + w * 32 + rg * 16 + l16;
        const short* qp = Qb + (((size_t)(b * 16 + h) * 2048 + s) << 7);
#pragma unroll
        for (int ks = 0; ks < 4; ++ks)
            qf[rg][ks] = *(const bh8*)(qp + ks * 32 + quad * 8);
    }

    // frag geometry (lane*8 folded into the bases):
    // K frag f of 32-key tile kt at kt*4096 + f*512 (f = nti*4+ks)
    // V frag nt of tile kt at (kt>>1)*8192 + (kt&1)*512 + nt*1024
    const short* kbase = Kpk + ((size_t)gb * 32) * 8192 + lane * 8;
    const short* vbase = Vpk + ((size_t)gb * 32) * 8192 + lane * 8;

    fx4 ctx[2][8];
#pragma unroll
    for (int rg = 0; rg < 2; ++rg)
#pragma unroll
        for (int j = 0; j < 8; ++j) ctx[rg][j] = fx4{0.f, 0.f, 0.f, 0.f};
    float l_part[2] = {0.f, 0.f};   // per-lane: q-row rg*16 + l16, this quad's keys

    // compute phase: swapped QK on resident K regs -> exp2/pack -> PV on vf.
    // sc[rg][nti][r] = score for q-row rg*16+l16, key quad*8 + nti*4 + r.
#define AT_COMPUTE(kX, vf)                                                      \
    do {                                                                        \
        fx4 sc[2][2];                                                           \
        sc[0][0] = fx4{0.f, 0.f, 0.f, 0.f}; sc[0][1] = fx4{0.f, 0.f, 0.f, 0.f}; \
        sc[1][0] = fx4{0.f, 0.f, 0.f, 0.f}; sc[1][1] = fx4{0.f, 0.f, 0.f, 0.f}; \
        __builtin_amdgcn_s_setprio(1);                                          \
        _Pragma("unroll")                                                       \
        for (int nti = 0; nti < 2; ++nti) {                                     \
            _Pragma("unroll")                                                   \
            for (int ks = 0; ks < 4; ++ks) {                                    \
                sc[0][nti] = __builtin_amdgcn_mfma_f32_16x16x32_bf16(kX[nti * 4 + ks], qf[0][ks], sc[0][nti], 0, 0, 0); \
                sc[1][nti] = __builtin_amdgcn_mfma_f32_16x16x32_bf16(kX[nti * 4 + ks], qf[1][ks], sc[1][nti], 0, 0, 0); \
            }                                                                   \
        }                                                                       \
        __builtin_amdgcn_s_setprio(0);                                          \
        bh8 pa[2];                                                              \
        _Pragma("unroll")                                                       \
        for (int rg = 0; rg < 2; ++rg) {                                        \
            float e0 = __builtin_amdgcn_exp2f(sc[rg][0][0]);                    \
            float e1 = __builtin_amdgcn_exp2f(sc[rg][0][1]);                    \
            float e2 = __builtin_amdgcn_exp2f(sc[rg][0][2]);                    \
            float e3 = __builtin_amdgcn_exp2f(sc[rg][0][3]);                    \
            float e4 = __builtin_amdgcn_exp2f(sc[rg][1][0]);                    \
            float e5 = __builtin_amdgcn_exp2f(sc[rg][1][1]);                    \
            float e6 = __builtin_amdgcn_exp2f(sc[rg][1][2]);                    \
            float e7 = __builtin_amdgcn_exp2f(sc[rg][1][3]);                    \
            l_part[rg] += ((e0 + e1) + (e2 + e3)) + ((e4 + e5) + (e6 + e7));    \
            unsigned a[4];                                                      \
            a[0] = pk_bf16(e0, e1);                                             \
            a[1] = pk_bf16(e2, e3);                                             \
            a[2] = pk_bf16(e4, e5);                                             \
            a[3] = pk_bf16(e6, e7);                                             \
            pa[rg] = *(const bh8*)a;                                            \
        }                                                                       \
        __builtin_amdgcn_s_setprio(1);                                          \
        _Pragma("unroll")                                                       \
        for (int nt = 0; nt < 8; ++nt) {                                        \
            ctx[0][nt] = __builtin_amdgcn_mfma_f32_16x16x32_bf16(pa[0], vf[nt], ctx[0][nt], 0, 0, 0); \
            ctx[1][nt] = __builtin_amdgcn_mfma_f32_16x16x32_bf16(pa[1], vf[nt], ctx[1][nt], 0, 0, 0); \
        }                                                                       \
        __builtin_amdgcn_s_setprio(0);                                          \
    } while (0)

    // ---- prologue: K tile 0 into kA ----
    bh8 kA[8], kB[8];
#pragma unroll
    for (int f = 0; f < 8; ++f)
        kA[f] = *(const bh8*)(kbase + f * 512);

    for (int kt = 0; kt < 64; kt += 2) {
        // even tile kt: V(kt) + prefetch K(kt+1) issued BEFORE compute;
        // QK runs on resident kA while those loads are in flight.
        {
            const short* vp = vbase + (size_t)(kt >> 1) * 8192;
            bh8 vf[8];
#pragma unroll
            for (int nt = 0; nt < 8; ++nt)
                vf[nt] = *(const bh8*)(vp + nt * 1024);
            const short* kp = kbase + (size_t)(kt + 1) * 4096;
#pragma unroll
            for (int f = 0; f < 8; ++f)
                kB[f] = *(const bh8*)(kp + f * 512);
            AT_COMPUTE(kA, vf);
        }
        // odd tile kt+1: V(kt+1) + prefetch K(kt+2) into kA (register dep
        // guarantees kA's last read in the NEXT QK... writes ordered by HW).
        {
            const short* vp = vbase + (size_t)(kt >> 1) * 8192 + 512;
            bh8 vf[8];
#pragma unroll
            for (int nt = 0; nt < 8; ++nt)
                vf[nt] = *(const bh8*)(vp + nt * 1024);
            if (kt < 62) {
                const short* kp = kbase + (size_t)(kt + 2) * 4096;
#pragma unroll
                for (int f = 0; f < 8; ++f)
                    kA[f] = *(const bh8*)(kp + f * 512);
            }
            AT_COMPUTE(kB, vf);
        }
    }
#undef AT_COMPUTE

    // ---- epilogue ----
    // ctx[rg][nt][r]: q-row qt*64 + w*32 + rg*16 + quad*4 + r, hd nt*16+l16.
    // l_part[rg]: partial rowsum for q-row rg*16+l16 over this quad's keys;
    // full rowsum = reduce across quads (xor 16, 32), then broadcast.
#pragma unroll
    for (int rg = 0; rg < 2; ++rg) {
        float lsum = l_part[rg];
        lsum += __shfl_xor(lsum, 16);
        lsum += __shfl_xor(lsum, 32);   // now rowsum(rg*16 + l16), all quads
        int srow = qt * 64 + w * 32 + rg * 16 + quad * 4;
#pragma unroll
        for (int r = 0; r < 4; ++r) {
            float inv = 1.f / __shfl(lsum, quad * 4 + r);
            size_t rowoff = ((size_t)b * 2048 + (srow + r)) * 2048 + h * 128;
#pragma unroll
            for (int nt = 0; nt < 8; ++nt)
                out[rowoff + nt * 16 + l16] = ctx[rg][nt][r] * inv;
        }
    }
}

// ---------------- launcher ----------------
extern "C" void kernel_launch(void* const* d_in, const int* in_sizes, int n_in,
                              void* d_out, int out_size, void* d_ws, size_t ws_size,
                              hipStream_t stream) {
    const float* hs = (const float*)d_in[0];
    const float* Wq = (const float*)d_in[1];
    const float* bq = (const float*)d_in[2];
    const float* Wk = (const float*)d_in[3];
    const float* bk = (const float*)d_in[4];
    const float* Wv = (const float*)d_in[5];
    const float* bv = (const float*)d_in[6];
    float* out = (float*)d_out;

    char* ws = (char*)d_ws;
    short* Xbf = (short*)(ws);                       // 16 MiB
    short* WqT = (short*)(ws + 16777216);            // 8 MiB
    short* WkT = (short*)(ws + 25165824);            // 2 MiB
    short* WvT = (short*)(ws + 27262976);            // 2 MiB
    short* Qb  = (short*)(ws + 29360128);            // 16 MiB
    short* Kpk = (short*)(ws + 46137344);            // 4 MiB
    short* Vpk = (short*)(ws + 50331648);            // 4 MiB

    prep_all<<<14336, 256, 0, stream>>>(hs, Xbf, Wq, WqT, Wk, WkT, Wv, WvT);
    proj_gemm<<<dim3(32, 24), 256, 0, stream>>>(Xbf, WqT, WkT, WvT, bq, bk, bv,
                                                Qb, Kpk, Vpk);
    attn<<<1024, 128, 0, stream>>>(Qb, Kpk, Vpk, out);
}

// Round 13
// 263.022 us; speedup vs baseline: 1.0100x; 1.0100x over previous
//
#include <hip/hip_runtime.h>
#include <hip/hip_bf16.h>

// ---------------- problem constants ----------------
#define QSCALE   0.08838834764831845f               // 1/sqrt(128)
#define QKSCALE  0.1275174468755322f                // QSCALE * log2(e)

typedef __attribute__((ext_vector_type(8))) short bh8;   // 8 bf16 (4 VGPRs)
typedef __attribute__((ext_vector_type(4))) float fx4;   // 4 fp32
typedef __attribute__((ext_vector_type(4))) short sh4;

typedef const __attribute__((address_space(1))) unsigned GAu;
typedef __attribute__((address_space(3))) unsigned LAu;

__device__ __forceinline__ short f2bf(float f) {
    unsigned u = __float_as_uint(f);
    unsigned r = u + 0x7fffu + ((u >> 16) & 1u);   // RNE
    return (short)(r >> 16);
}

__device__ __forceinline__ unsigned pk_bf16(float x, float y) {
    union { __hip_bfloat162 h; unsigned u; } cv;
    cv.h = __float22bfloat162_rn(float2{x, y});    // x -> low short, y -> high short
    return cv.u;
}

// ---------------- fused prep v2: X cvt + 3 weight transposes, wide I/O (R13) ----------------
// R12 accounting: proj(~94) + attn(~90) + trivial cvt leave a ~60us residual
// that launch-fusion barely dented -> it lives in the transpose branch
// (32x32 tiles: 128B-row reads, 64B bf16-row writes = 1/8 write coalescing).
// R13: 64x64 tiles; float4 global reads; LDS fp32 tile[64][65]; short4 (8B)
// writes -> 512B per wave across 4 rows (4x wider). 1536 transpose blocks
// (was 6144).
//   blocks [0,8192)     : cvt X fp32 -> bf16 (1 float4/thread)
//   blocks [8192,9216)  : transpose Wq [2048][2048] -> WqT (32x32 tiles of 64)
//   blocks [9216,9472)  : transpose Wk [2048][512]  -> WkT (8x32 tiles)
//   blocks [9472,9728)  : transpose Wv [2048][512]  -> WvT (8x32 tiles)
__global__ __launch_bounds__(256) void prep_all(
    const float* __restrict__ x,  short* __restrict__ xo,
    const float* __restrict__ wq, short* __restrict__ wqt,
    const float* __restrict__ wk, short* __restrict__ wkt,
    const float* __restrict__ wv, short* __restrict__ wvt) {
    __shared__ float tile[64][65];
    const int bid = blockIdx.x;
    const int tid = threadIdx.x;

    if (bid < 8192) {
        int i = bid * 256 + tid;
        float4 v = ((const float4*)x)[i];
        sh4 s;
        s.x = f2bf(v.x); s.y = f2bf(v.y); s.z = f2bf(v.z); s.w = f2bf(v.w);
        ((sh4*)xo)[i] = s;
        return;
    }

    const float* w; short* wt; int N, nb, kb;
    int t = bid - 8192;
    if (t < 1024)      { w = wq; wt = wqt; N = 2048; nb = t & 31; kb = t >> 5; }
    else if (t < 1280) { w = wk; wt = wkt; N = 512;  t -= 1024; nb = t & 7; kb = t >> 3; }
    else               { w = wv; wt = wvt; N = 512;  t -= 1280; nb = t & 7; kb = t >> 3; }
    const int K = 2048;

    // read: 64 rows (k) x 64 cols (n), float4 per thread x 4 passes
    {
        int c4 = tid & 15, r0 = tid >> 4;
#pragma unroll
        for (int rr = 0; rr < 4; ++rr) {
            int r = r0 + rr * 16;
            float4 v = *(const float4*)&w[(size_t)(kb * 64 + r) * N + nb * 64 + c4 * 4];
            *(float4*)&tile[r][c4 * 4] = v;
        }
    }
    __syncthreads();
    // write: WT row n gets k-run; short4 per thread x 4 passes
    {
        int k4 = tid & 15, n0 = tid >> 4;
#pragma unroll
        for (int rr = 0; rr < 4; ++rr) {
            int n = n0 + rr * 16;
            sh4 s;
            s.x = f2bf(tile[k4 * 4 + 0][n]);
            s.y = f2bf(tile[k4 * 4 + 1][n]);
            s.z = f2bf(tile[k4 * 4 + 2][n]);
            s.w = f2bf(tile[k4 * 4 + 3][n]);
            *(sh4*)&wt[(size_t)(nb * 64 + n) * K + kb * 64 + k4 * 4] = s;
        }
    }
}

// ---------------- fused QKV projection GEMM (static double-buffer, R4 form) ----------------
// C[4096 x 3072]: n-tiles 0..15 -> Q, 16..19 -> K, 20..23 -> V
// Verified at ~93us (R9/R11). R10's counted-vmcnt port REGRESSED here
// (4-wave lockstep: extra barriers cost more than the drain they removed) --
// keep the R4 schedule: static-named dbuf, stage(next) before compute(cur),
// one __syncthreads per tile.
// R7 Kpk packing (for swapped-QK attn): frag (b,g,kt32,nti,ks): key u = s&31
// maps to group nti=(u>>2)&1, frag row fl16=(u>>3)*4+(u&3); lane=qd*16+fl16,
// j<8 holds K[key][ks*32+qd*8+j]. Swapped QK^T then lands lane-exact as the
// PV A-fragment. Vpk unchanged.
__global__ __launch_bounds__(256) void proj_gemm(
    const short* __restrict__ X,     // [4096][2048] bf16
    const short* __restrict__ WqT,   // [2048][2048] bf16 (N-major)
    const short* __restrict__ WkT,   // [512][2048]
    const short* __restrict__ WvT,   // [512][2048]
    const float* __restrict__ bq, const float* __restrict__ bk,
    const float* __restrict__ bv,
    short* __restrict__ Qb, short* __restrict__ Kpk, short* __restrict__ Vpk) {
    __shared__ short As0[128 * 32];
    __shared__ short As1[128 * 32];
    __shared__ short Bs0[128 * 32];
    __shared__ short Bs1[128 * 32];

    const int tid = threadIdx.x;
    const int bm = blockIdx.x;      // 0..31
    const int ntg = blockIdx.y;     // 0..23

    const short* Wm; const float* bias; int col0, kind;
    if (ntg < 16)      { Wm = WqT; bias = bq; col0 = ntg * 128;        kind = 0; }
    else if (ntg < 20) { Wm = WkT; bias = bk; col0 = (ntg - 16) * 128; kind = 1; }
    else               { Wm = WvT; bias = bv; col0 = (ntg - 20) * 128; kind = 2; }

    const int w = tid >> 6, lane = tid & 63, quad = lane >> 4, l16 = lane & 15;

    fx4 acc[2][8];
#pragma unroll
    for (int i = 0; i < 2; ++i)
#pragma unroll
        for (int j = 0; j < 8; ++j) acc[i][j] = fx4{0.f, 0.f, 0.f, 0.f};

    const int srow = w * 16 + (lane >> 2);
    const int scol = (((lane & 3) ^ ((lane >> 2) & 3)) * 8);
    const short* Ag = X + (size_t)(bm * 128 + srow) * 2048 + scol;
    const short* Bg = Wm + (size_t)(col0 + srow) * 2048 + scol;
    const int stoff = w * 512;      // per-wave LDS staging offset

    const int fchunk = (quad ^ (l16 & 3)) * 8;
    const int aoff0 = (w * 32 + l16) * 32 + fchunk;       // A rows w*32+l16
    const int aoff1 = aoff0 + 512;                        // A rows w*32+16+l16
    const int boff  = l16 * 32 + fchunk;                  // B row nt*16+l16 base

    // hoisted read pointers (all compile-time offsets from static arrays)
    const short* pA00 = As0 + aoff0;  const short* pA01 = As0 + aoff1;
    const short* pA10 = As1 + aoff0;  const short* pA11 = As1 + aoff1;
    const short* pB0  = Bs0 + boff;   const short* pB1  = Bs1 + boff;

#define PG_STAGE(AsD, BsD, ktile)                                               \
    do {                                                                        \
        const int k0_ = (ktile) * 32;                                           \
        _Pragma("unroll")                                                       \
        for (int j = 0; j < 2; ++j) {                                           \
            __builtin_amdgcn_global_load_lds(                                   \
                (GAu*)(Ag + (size_t)(j * 64) * 2048 + k0_),                     \
                (LAu*)(AsD + stoff + j * 2048), 16, 0, 0);                      \
            __builtin_amdgcn_global_load_lds(                                   \
                (GAu*)(Bg + (size_t)(j * 64) * 2048 + k0_),                     \
                (LAu*)(BsD + stoff + j * 2048), 16, 0, 0);                      \
        }                                                                       \
    } while (0)

#define PG_COMPUTE(pA0_, pA1_, pB_)                                             \
    do {                                                                        \
        bh8 af0 = *(const bh8*)(pA0_);                                          \
        bh8 af1 = *(const bh8*)(pA1_);                                          \
        _Pragma("unroll")                                                       \
        for (int nt = 0; nt < 8; ++nt) {                                        \
            bh8 bf = *(const bh8*)((pB_) + nt * 512);                           \
            acc[0][nt] = __builtin_amdgcn_mfma_f32_16x16x32_bf16(af0, bf, acc[0][nt], 0, 0, 0); \
            acc[1][nt] = __builtin_amdgcn_mfma_f32_16x16x32_bf16(af1, bf, acc[1][nt], 0, 0, 0); \
        }                                                                       \
    } while (0)

    // ---- prologue: stage k-tile 0 into buffer 0 ----
    PG_STAGE(As0, Bs0, 0);
    __syncthreads();   // one exposed drain, prologue only

    for (int kt = 0; kt < 64; kt += 2) {
        // body A: stage odd tile kt+1 into buf1; compute even tile kt from buf0
        PG_STAGE(As1, Bs1, kt + 1);
        PG_COMPUTE(pA00, pA01, pB0);
        __syncthreads();   // drains stage(kt+1); fences buf0 reuse below

        // body B: stage even tile kt+2 into buf0; compute odd tile kt+1 from buf1
        if (kt < 62) PG_STAGE(As0, Bs0, kt + 2);
        PG_COMPUTE(pA10, pA11, pB1);
        __syncthreads();   // drains stage(kt+2); fences buf1 reuse next iter
    }
#undef PG_STAGE
#undef PG_COMPUTE

    // epilogue: row = bm*128 + w*32 + mt*16 + quad*4 + r ; col = col0 + nt*16 + l16
#pragma unroll
    for (int mt = 0; mt < 2; ++mt) {
        int srow2 = bm * 128 + w * 32 + mt * 16 + quad * 4;
#pragma unroll
        for (int nt = 0; nt < 8; ++nt) {
            int c = col0 + nt * 16 + l16;
            float bval = bias[c];
#pragma unroll
            for (int r = 0; r < 4; ++r) {
                int sg = srow2 + r;
                int b = sg >> 11, s = sg & 2047;
                float v = acc[mt][nt][r] + bval;
                int hd = c & 127;
                if (kind == 0) {
                    v *= QKSCALE;  // fold 1/sqrt(d)*log2(e) into Q
                    int h = c >> 7;
                    Qb[(((size_t)(b * 16 + h) * 2048 + s) << 7) + hd] = f2bf(v);
                } else if (kind == 1) {
                    // R7 interleaved packing for swapped-QK (see attn)
                    int g = c >> 7;
                    int kt32 = s >> 5, u = s & 31;
                    int nti = (u >> 2) & 1, fl16 = (u >> 3) * 4 + (u & 3);
                    int ks = hd >> 5, qd = (hd >> 3) & 3, j = hd & 7;
                    size_t frag = (((size_t)(b * 4 + g) * 64 + kt32) * 8 + nti * 4 + ks);
                    Kpk[frag * 512 + (qd * 16 + fl16) * 8 + j] = f2bf(v);
                } else {
                    int g = c >> 7;
                    int ktt = s >> 6, tl = s & 63;
                    int ts = tl >> 5, qd = (tl >> 3) & 3, j = tl & 7;
                    int fnt = hd >> 4, fl16 = hd & 15;
                    size_t frag = (((size_t)(b * 4 + g) * 32 + ktt) * 16 + fnt * 2 + ts);
                    Vpk[frag * 512 + (qd * 16 + fl16) * 8 + j] = f2bf(v);
                }
            }
        }
    }
}

// ---------------- flash attention: counted-vmcnt pipeline, race-fixed (R9) ----------------
// Validated in R9 (best config, 260.9us total in R11): every barrier is
// `s_waitcnt lgkmcnt(0); s_barrier` (__syncthreads semantics minus only the
// vmcnt(0) drain); counted vmcnt(8) keeps a full stage in flight across each
// compute phase. Two vmcnt(0) total: prologue + tail. Swapped QK^T (R7): P
// lands lane-exact as the PV A-fragment -- no LDS round-trip, no v_perm,
// bank conflicts = 0. R12's zero-LDS L2-direct variant was neutral-to-worse
// (extra L2 traffic canceled the sync savings) -- reverted.
// 1024 blocks; 128 threads = 2 waves x 32 q-rows; LDS = 32768 B.
__global__ __launch_bounds__(128, 2) void attn(
    const short* __restrict__ Qb,   // [B][HQ][S][128] bf16, pre-scaled by QKSCALE
    const short* __restrict__ Kpk,  // packed A-frags (interleaved keys)
    const short* __restrict__ Vpk,  // packed B-frags
    float* __restrict__ out) {      // [B][S][D] fp32
    __shared__ short Ks0[8 * 512];                   // 8 KB: K tile (even)
    __shared__ short Ks1[8 * 512];                   // 8 KB: K tile (odd)
    __shared__ short Vs0[8 * 512];                   // 8 KB: V tile (even)
    __shared__ short Vs1[8 * 512];                   // 8 KB: V tile (odd)

    const int bid = blockIdx.x;
    const int gb = bid & 7;              // XCD selector = (b*4+g)
    const int rep = (bid >> 3) & 3;
    const int qt = bid >> 5;             // 0..31
    const int b = gb >> 2, g = gb & 3;
    const int h = rep * 4 + g;
    const int tid = threadIdx.x, w = tid >> 6, lane = tid & 63;
    const int quad = lane >> 4, l16 = lane & 15;

    // Q fragments: wave w owns rows qt*64 + w*32 + rg*16 + l16 (as B operand)
    bh8 qf[2][4];
#pragma unroll
    for (int rg = 0; rg < 2; ++rg) {
        int s = qt * 64 + w * 32 + rg * 16 + l16;
        const short* qp = Qb + (((size_t)(b * 16 + h) * 2048 + s) << 7);
#pragma unroll
        for (int ks = 0; ks < 4; ++ks)
            qf[rg][ks] = *(const bh8*)(qp + ks * 32 + quad * 8);
    }

    // frag geometry: K frags for 32-key tile kt contiguous at kt*4096
    // (frag idx = kt*8 + nti*4 + ks). V frags for tile kt: base
    // (kt>>1)*8192 + (kt&1)*512, stride 1024 shorts.
    const short* kbase = Kpk + ((size_t)gb * 32) * 8192;
    const short* vbase = Vpk + ((size_t)gb * 32) * 8192;

    // hoisted per-lane LDS read pointers (compile-time offsets thereafter)
    const short* pK0 = Ks0 + lane * 8;
    const short* pK1 = Ks1 + lane * 8;
    const short* pV0 = Vs0 + lane * 8;
    const short* pV1 = Vs1 + lane * 8;

    fx4 ctx[2][8];
#pragma unroll
    for (int rg = 0; rg < 2; ++rg)
#pragma unroll
        for (int j = 0; j < 8; ++j) ctx[rg][j] = fx4{0.f, 0.f, 0.f, 0.f};
    float l_part[2] = {0.f, 0.f};   // per-lane: q-row rg*16 + l16, this quad's keys

// barrier with LDS-read drain: __syncthreads semantics minus the vmcnt drain.
// lgkmcnt(0) guarantees no in-flight ds_read crosses into the buffer-overwrite
// region (the R8 race); it is ~free since reads are consumed just before.
#define AT_BARRIER()  asm volatile("s_waitcnt lgkmcnt(0)\n\ts_barrier" ::: "memory")
#define AT_VM(N)      asm volatile("s_waitcnt vmcnt(" #N ")" ::: "memory")

    // stage tile `kn` into statically-named dest buffers; wave w loads
    // K frags w*4..w*4+3 and V frags w*4..w*4+3 (8 gload_lds per wave)
#define AT_STAGE(KsD, VsD, kn)                                                  \
    do {                                                                        \
        const short* kp_ = kbase + (size_t)(kn) * 4096;                         \
        const short* vp_ = vbase + (size_t)((kn) >> 1) * 8192 + ((kn) & 1) * 512;\
        _Pragma("unroll")                                                       \
        for (int i = 0; i < 4; ++i) {                                           \
            int f = w * 4 + i;                                                  \
            __builtin_amdgcn_global_load_lds((GAu*)(kp_ + f * 512 + lane * 8),  \
                                             (LAu*)(KsD + f * 512), 16, 0, 0);  \
            __builtin_amdgcn_global_load_lds((GAu*)(vp_ + (size_t)f * 1024 + lane * 8),\
                                             (LAu*)(VsD + f * 512), 16, 0, 0);  \
        }                                                                       \
    } while (0)

    // compute phase on tile at (pKC,pVC): swapped QK -> exp2/pack -> PV.
    // sc[rg][nti][r] = score for q-row rg*16+l16, key quad*8 + nti*4 + r.
#define AT_COMPUTE(pKC, pVC)                                                    \
    do {                                                                        \
        fx4 sc[2][2];                                                           \
        sc[0][0] = fx4{0.f, 0.f, 0.f, 0.f}; sc[0][1] = fx4{0.f, 0.f, 0.f, 0.f}; \
        sc[1][0] = fx4{0.f, 0.f, 0.f, 0.f}; sc[1][1] = fx4{0.f, 0.f, 0.f, 0.f}; \
        __builtin_amdgcn_s_setprio(1);                                          \
        _Pragma("unroll")                                                       \
        for (int nti = 0; nti < 2; ++nti) {                                     \
            _Pragma("unroll")                                                   \
            for (int ks = 0; ks < 4; ++ks) {                                    \
                bh8 kf = *(const bh8*)((pKC) + (nti * 4 + ks) * 512);           \
                sc[0][nti] = __builtin_amdgcn_mfma_f32_16x16x32_bf16(kf, qf[0][ks], sc[0][nti], 0, 0, 0); \
                sc[1][nti] = __builtin_amdgcn_mfma_f32_16x16x32_bf16(kf, qf[1][ks], sc[1][nti], 0, 0, 0); \
            }                                                                   \
        }                                                                       \
        __builtin_amdgcn_s_setprio(0);                                          \
        bh8 pa[2];                                                              \
        _Pragma("unroll")                                                       \
        for (int rg = 0; rg < 2; ++rg) {                                        \
            float e0 = __builtin_amdgcn_exp2f(sc[rg][0][0]);                    \
            float e1 = __builtin_amdgcn_exp2f(sc[rg][0][1]);                    \
            float e2 = __builtin_amdgcn_exp2f(sc[rg][0][2]);                    \
            float e3 = __builtin_amdgcn_exp2f(sc[rg][0][3]);                    \
            float e4 = __builtin_amdgcn_exp2f(sc[rg][1][0]);                    \
            float e5 = __builtin_amdgcn_exp2f(sc[rg][1][1]);                    \
            float e6 = __builtin_amdgcn_exp2f(sc[rg][1][2]);                    \
            float e7 = __builtin_amdgcn_exp2f(sc[rg][1][3]);                    \
            l_part[rg] += ((e0 + e1) + (e2 + e3)) + ((e4 + e5) + (e6 + e7));    \
            unsigned a[4];                                                      \
            a[0] = pk_bf16(e0, e1);                                             \
            a[1] = pk_bf16(e2, e3);                                             \
            a[2] = pk_bf16(e4, e5);                                             \
            a[3] = pk_bf16(e6, e7);                                             \
            pa[rg] = *(const bh8*)a;                                            \
        }                                                                       \
        __builtin_amdgcn_s_setprio(1);                                          \
        _Pragma("unroll")                                                       \
        for (int nt = 0; nt < 8; ++nt) {                                        \
            bh8 vf = *(const bh8*)((pVC) + nt * 512);                           \
            ctx[0][nt] = __builtin_amdgcn_mfma_f32_16x16x32_bf16(pa[0], vf, ctx[0][nt], 0, 0, 0); \
            ctx[1][nt] = __builtin_amdgcn_mfma_f32_16x16x32_bf16(pa[1], vf, ctx[1][nt], 0, 0, 0); \
        }                                                                       \
        __builtin_amdgcn_s_setprio(0);                                          \
    } while (0)

    // ---- prologue: stage tiles 0 and 1; single exposed drain ----
    AT_STAGE(Ks0, Vs0, 0);
    AT_STAGE(Ks1, Vs1, 1);
    AT_VM(0);          // tiles 0,1 landed (this wave)
    AT_BARRIER();      // visible to both waves

    // steady state per body: enter with buf holding tile kt (landed) and
    // stage(kt+1) 8-outstanding (after first iter).
    for (int kt = 0; kt < 62; kt += 2) {
        AT_COMPUTE(pK0, pV0);            // tile kt from buf0
        AT_BARRIER();                    // all waves' buf0 reads COMPLETE
        AT_STAGE(Ks0, Vs0, kt + 2);      // overwrite buf0 (in flight)
        AT_VM(8);                        // tile kt+1 landed (issued a full phase ago)
        AT_BARRIER();                    // tile kt+1 visible
        AT_COMPUTE(pK1, pV1);            // tile kt+1 from buf1
        AT_BARRIER();                    // all waves' buf1 reads COMPLETE
        AT_STAGE(Ks1, Vs1, kt + 3);      // overwrite buf1 (kt+3 <= 63)
        AT_VM(8);                        // tile kt+2 landed
        AT_BARRIER();                    // tile kt+2 visible
    }
    // ---- tail: tiles 62 (landed in buf0), 63 (8-outstanding into buf1) ----
    AT_COMPUTE(pK0, pV0);                // tile 62
    AT_VM(0);                            // tile 63 landed
    AT_BARRIER();                        // visible
    AT_COMPUTE(pK1, pV1);                // tile 63
#undef AT_STAGE
#undef AT_COMPUTE
#undef AT_BARRIER
#undef AT_VM

    // ---- epilogue ----
    // ctx[rg][nt][r]: q-row qt*64 + w*32 + rg*16 + quad*4 + r, hd nt*16+l16.
    // l_part[rg]: partial rowsum for q-row rg*16+l16 over this quad's keys;
    // full rowsum = reduce across quads (xor 16, 32), then broadcast.
#pragma unroll
    for (int rg = 0; rg < 2; ++rg) {
        float lsum = l_part[rg];
        lsum += __shfl_xor(lsum, 16);
        lsum += __shfl_xor(lsum, 32);   // now rowsum(rg*16 + l16), all quads
        int srow = qt * 64 + w * 32 + rg * 16 + quad * 4;
#pragma unroll
        for (int r = 0; r < 4; ++r) {
            float inv = 1.f / __shfl(lsum, quad * 4 + r);
            size_t rowoff = ((size_t)b * 2048 + (srow + r)) * 2048 + h * 128;
#pragma unroll
            for (int nt = 0; nt < 8; ++nt)
                out[rowoff + nt * 16 + l16] = ctx[rg][nt][r] * inv;
        }
    }
}

// ---------------- launcher ----------------
extern "C" void kernel_launch(void* const* d_in, const int* in_sizes, int n_in,
                              void* d_out, int out_size, void* d_ws, size_t ws_size,
                              hipStream_t stream) {
    const float* hs = (const float*)d_in[0];
    const float* Wq = (const float*)d_in[1];
    const float* bq = (const float*)d_in[2];
    const float* Wk = (const float*)d_in[3];
    const float* bk = (const float*)d_in[4];
    const float* Wv = (const float*)d_in[5];
    const float* bv = (const float*)d_in[6];
    float* out = (float*)d_out;

    char* ws = (char*)d_ws;
    short* Xbf = (short*)(ws);                       // 16 MiB
    short* WqT = (short*)(ws + 16777216);            // 8 MiB
    short* WkT = (short*)(ws + 25165824);            // 2 MiB
    short* WvT = (short*)(ws + 27262976);            // 2 MiB
    short* Qb  = (short*)(ws + 29360128);            // 16 MiB
    short* Kpk = (short*)(ws + 46137344);            // 4 MiB
    short* Vpk = (short*)(ws + 50331648);            // 4 MiB

    prep_all<<<9728, 256, 0, stream>>>(hs, Xbf, Wq, WqT, Wk, WkT, Wv, WvT);
    proj_gemm<<<dim3(32, 24), 256, 0, stream>>>(Xbf, WqT, WkT, WvT, bq, bk, bv,
                                                Qb, Kpk, Vpk);
    attn<<<1024, 128, 0, stream>>>(Qb, Kpk, Vpk, out);
}

// Round 14
// 257.998 us; speedup vs baseline: 1.0297x; 1.0195x over previous
//
#include <hip/hip_runtime.h>
#include <hip/hip_bf16.h>

// ---------------- problem constants ----------------
#define QSCALE   0.08838834764831845f               // 1/sqrt(128)
#define QKSCALE  0.1275174468755322f                // QSCALE * log2(e)

typedef __attribute__((ext_vector_type(8))) short bh8;   // 8 bf16 (4 VGPRs)
typedef __attribute__((ext_vector_type(4))) float fx4;   // 4 fp32
typedef __attribute__((ext_vector_type(4))) short sh4;

typedef const __attribute__((address_space(1))) unsigned GAu;
typedef __attribute__((address_space(3))) unsigned LAu;

__device__ __forceinline__ short f2bf(float f) {
    unsigned u = __float_as_uint(f);
    unsigned r = u + 0x7fffu + ((u >> 16) & 1u);   // RNE
    return (short)(r >> 16);
}

__device__ __forceinline__ unsigned pk_bf16(float x, float y) {
    union { __hip_bfloat162 h; unsigned u; } cv;
    cv.h = __float22bfloat162_rn(float2{x, y});    // x -> low short, y -> high short
    return cv.u;
}

// ---------------- fused prep v2: X cvt + 3 weight transposes, wide I/O (R13) ----------------
//   blocks [0,8192)     : cvt X fp32 -> bf16 (1 float4/thread)
//   blocks [8192,9216)  : transpose Wq [2048][2048] -> WqT (32x32 tiles of 64)
//   blocks [9216,9472)  : transpose Wk [2048][512]  -> WkT (8x32 tiles)
//   blocks [9472,9728)  : transpose Wv [2048][512]  -> WvT (8x32 tiles)
__global__ __launch_bounds__(256) void prep_all(
    const float* __restrict__ x,  short* __restrict__ xo,
    const float* __restrict__ wq, short* __restrict__ wqt,
    const float* __restrict__ wk, short* __restrict__ wkt,
    const float* __restrict__ wv, short* __restrict__ wvt) {
    __shared__ float tile[64][65];
    const int bid = blockIdx.x;
    const int tid = threadIdx.x;

    if (bid < 8192) {
        int i = bid * 256 + tid;
        float4 v = ((const float4*)x)[i];
        sh4 s;
        s.x = f2bf(v.x); s.y = f2bf(v.y); s.z = f2bf(v.z); s.w = f2bf(v.w);
        ((sh4*)xo)[i] = s;
        return;
    }

    const float* w; short* wt; int N, nb, kb;
    int t = bid - 8192;
    if (t < 1024)      { w = wq; wt = wqt; N = 2048; nb = t & 31; kb = t >> 5; }
    else if (t < 1280) { w = wk; wt = wkt; N = 512;  t -= 1024; nb = t & 7; kb = t >> 3; }
    else               { w = wv; wt = wvt; N = 512;  t -= 1280; nb = t & 7; kb = t >> 3; }
    const int K = 2048;

    // read: 64 rows (k) x 64 cols (n), float4 per thread x 4 passes
    {
        int c4 = tid & 15, r0 = tid >> 4;
#pragma unroll
        for (int rr = 0; rr < 4; ++rr) {
            int r = r0 + rr * 16;
            float4 v = *(const float4*)&w[(size_t)(kb * 64 + r) * N + nb * 64 + c4 * 4];
            *(float4*)&tile[r][c4 * 4] = v;
        }
    }
    __syncthreads();
    // write: WT row n gets k-run; short4 per thread x 4 passes
    {
        int k4 = tid & 15, n0 = tid >> 4;
#pragma unroll
        for (int rr = 0; rr < 4; ++rr) {
            int n = n0 + rr * 16;
            sh4 s;
            s.x = f2bf(tile[k4 * 4 + 0][n]);
            s.y = f2bf(tile[k4 * 4 + 1][n]);
            s.z = f2bf(tile[k4 * 4 + 2][n]);
            s.w = f2bf(tile[k4 * 4 + 3][n]);
            *(sh4*)&wt[(size_t)(nb * 64 + n) * K + kb * 64 + k4 * 4] = s;
        }
    }
}

// ---------------- fused QKV projection GEMM (static double-buffer, R4 form) ----------------
// C[4096 x 3072]: n-tiles 0..15 -> Q, 16..19 -> K, 20..23 -> V
// Verified at ~93-95us (R9/R11/R13). R10's counted-vmcnt port REGRESSED here
// (4-wave lockstep: extra barriers cost more than the drain they removed) --
// keep the R4 schedule: static-named dbuf, stage(next) before compute(cur),
// one __syncthreads per tile.
// R7 Kpk packing (for swapped-QK attn): frag (b,g,kt32,nti,ks): key u = s&31
// maps to group nti=(u>>2)&1, frag row fl16=(u>>3)*4+(u&3); lane=qd*16+fl16,
// j<8 holds K[key][ks*32+qd*8+j]. Swapped QK^T then lands lane-exact as the
// PV A-fragment. Vpk unchanged.
__global__ __launch_bounds__(256) void proj_gemm(
    const short* __restrict__ X,     // [4096][2048] bf16
    const short* __restrict__ WqT,   // [2048][2048] bf16 (N-major)
    const short* __restrict__ WkT,   // [512][2048]
    const short* __restrict__ WvT,   // [512][2048]
    const float* __restrict__ bq, const float* __restrict__ bk,
    const float* __restrict__ bv,
    short* __restrict__ Qb, short* __restrict__ Kpk, short* __restrict__ Vpk) {
    __shared__ short As0[128 * 32];
    __shared__ short As1[128 * 32];
    __shared__ short Bs0[128 * 32];
    __shared__ short Bs1[128 * 32];

    const int tid = threadIdx.x;
    const int bm = blockIdx.x;      // 0..31
    const int ntg = blockIdx.y;     // 0..23

    const short* Wm; const float* bias; int col0, kind;
    if (ntg < 16)      { Wm = WqT; bias = bq; col0 = ntg * 128;        kind = 0; }
    else if (ntg < 20) { Wm = WkT; bias = bk; col0 = (ntg - 16) * 128; kind = 1; }
    else               { Wm = WvT; bias = bv; col0 = (ntg - 20) * 128; kind = 2; }

    const int w = tid >> 6, lane = tid & 63, quad = lane >> 4, l16 = lane & 15;

    fx4 acc[2][8];
#pragma unroll
    for (int i = 0; i < 2; ++i)
#pragma unroll
        for (int j = 0; j < 8; ++j) acc[i][j] = fx4{0.f, 0.f, 0.f, 0.f};

    const int srow = w * 16 + (lane >> 2);
    const int scol = (((lane & 3) ^ ((lane >> 2) & 3)) * 8);
    const short* Ag = X + (size_t)(bm * 128 + srow) * 2048 + scol;
    const short* Bg = Wm + (size_t)(col0 + srow) * 2048 + scol;
    const int stoff = w * 512;      // per-wave LDS staging offset

    const int fchunk = (quad ^ (l16 & 3)) * 8;
    const int aoff0 = (w * 32 + l16) * 32 + fchunk;       // A rows w*32+l16
    const int aoff1 = aoff0 + 512;                        // A rows w*32+16+l16
    const int boff  = l16 * 32 + fchunk;                  // B row nt*16+l16 base

    // hoisted read pointers (all compile-time offsets from static arrays)
    const short* pA00 = As0 + aoff0;  const short* pA01 = As0 + aoff1;
    const short* pA10 = As1 + aoff0;  const short* pA11 = As1 + aoff1;
    const short* pB0  = Bs0 + boff;   const short* pB1  = Bs1 + boff;

#define PG_STAGE(AsD, BsD, ktile)                                               \
    do {                                                                        \
        const int k0_ = (ktile) * 32;                                           \
        _Pragma("unroll")                                                       \
        for (int j = 0; j < 2; ++j) {                                           \
            __builtin_amdgcn_global_load_lds(                                   \
                (GAu*)(Ag + (size_t)(j * 64) * 2048 + k0_),                     \
                (LAu*)(AsD + stoff + j * 2048), 16, 0, 0);                      \
            __builtin_amdgcn_global_load_lds(                                   \
                (GAu*)(Bg + (size_t)(j * 64) * 2048 + k0_),                     \
                (LAu*)(BsD + stoff + j * 2048), 16, 0, 0);                      \
        }                                                                       \
    } while (0)

#define PG_COMPUTE(pA0_, pA1_, pB_)                                             \
    do {                                                                        \
        bh8 af0 = *(const bh8*)(pA0_);                                          \
        bh8 af1 = *(const bh8*)(pA1_);                                          \
        _Pragma("unroll")                                                       \
        for (int nt = 0; nt < 8; ++nt) {                                        \
            bh8 bf = *(const bh8*)((pB_) + nt * 512);                           \
            acc[0][nt] = __builtin_amdgcn_mfma_f32_16x16x32_bf16(af0, bf, acc[0][nt], 0, 0, 0); \
            acc[1][nt] = __builtin_amdgcn_mfma_f32_16x16x32_bf16(af1, bf, acc[1][nt], 0, 0, 0); \
        }                                                                       \
    } while (0)

    // ---- prologue: stage k-tile 0 into buffer 0 ----
    PG_STAGE(As0, Bs0, 0);
    __syncthreads();   // one exposed drain, prologue only

    for (int kt = 0; kt < 64; kt += 2) {
        // body A: stage odd tile kt+1 into buf1; compute even tile kt from buf0
        PG_STAGE(As1, Bs1, kt + 1);
        PG_COMPUTE(pA00, pA01, pB0);
        __syncthreads();   // drains stage(kt+1); fences buf0 reuse below

        // body B: stage even tile kt+2 into buf0; compute odd tile kt+1 from buf1
        if (kt < 62) PG_STAGE(As0, Bs0, kt + 2);
        PG_COMPUTE(pA10, pA11, pB1);
        __syncthreads();   // drains stage(kt+2); fences buf1 reuse next iter
    }
#undef PG_STAGE
#undef PG_COMPUTE

    // epilogue: row = bm*128 + w*32 + mt*16 + quad*4 + r ; col = col0 + nt*16 + l16
#pragma unroll
    for (int mt = 0; mt < 2; ++mt) {
        int srow2 = bm * 128 + w * 32 + mt * 16 + quad * 4;
#pragma unroll
        for (int nt = 0; nt < 8; ++nt) {
            int c = col0 + nt * 16 + l16;
            float bval = bias[c];
#pragma unroll
            for (int r = 0; r < 4; ++r) {
                int sg = srow2 + r;
                int b = sg >> 11, s = sg & 2047;
                float v = acc[mt][nt][r] + bval;
                int hd = c & 127;
                if (kind == 0) {
                    v *= QKSCALE;  // fold 1/sqrt(d)*log2(e) into Q
                    int h = c >> 7;
                    Qb[(((size_t)(b * 16 + h) * 2048 + s) << 7) + hd] = f2bf(v);
                } else if (kind == 1) {
                    // R7 interleaved packing for swapped-QK (see attn)
                    int g = c >> 7;
                    int kt32 = s >> 5, u = s & 31;
                    int nti = (u >> 2) & 1, fl16 = (u >> 3) * 4 + (u & 3);
                    int ks = hd >> 5, qd = (hd >> 3) & 3, j = hd & 7;
                    size_t frag = (((size_t)(b * 4 + g) * 64 + kt32) * 8 + nti * 4 + ks);
                    Kpk[frag * 512 + (qd * 16 + fl16) * 8 + j] = f2bf(v);
                } else {
                    int g = c >> 7;
                    int ktt = s >> 6, tl = s & 63;
                    int ts = tl >> 5, qd = (tl >> 3) & 3, j = tl & 7;
                    int fnt = hd >> 4, fl16 = hd & 15;
                    size_t frag = (((size_t)(b * 4 + g) * 32 + ktt) * 16 + fnt * 2 + ts);
                    Vpk[frag * 512 + (qd * 16 + fl16) * 8 + j] = f2bf(v);
                }
            }
        }
    }
}

// ---------------- flash attention: cross-tile PV pipeline (R14) ----------------
// R13 state: attn <95us at ~31% MfmaUtil; the one modeled serial gap is the
// per-tile QK -> softmax -> PV chain (softmax VALU sits between two MFMA
// clusters; both waves barrier-lockstep -> MFMA pipe idles every softmax).
// R14 (T15 mechanism): phase t computes PV(t-1) instead of PV(t). P(t-1) is
// already in registers, so the stream is QK(t)+PV(t-1) = 32 back-to-back
// MFMAs, and softmax(t) issues into the MFMA pipe's shadow. V must outlive
// its LDS buffer (stage(t+1) overwrites it) -> V read to registers at phase
// start, ping-ponged via statically-named vfA/vfB (R4 lesson). First-tile
// PV is a no-op via zero paP/vfB; final PV(63) peeled after the tail.
// Sync structure BYTE-IDENTICAL to R9 (validated deterministic): barriers =
// `s_waitcnt lgkmcnt(0); s_barrier`, counted vmcnt(8), two vmcnt(0) total.
// 1024 blocks; 128 threads = 2 waves x 32 q-rows; LDS = 32768 B.
__global__ __launch_bounds__(128, 2) void attn(
    const short* __restrict__ Qb,   // [B][HQ][S][128] bf16, pre-scaled by QKSCALE
    const short* __restrict__ Kpk,  // packed A-frags (interleaved keys)
    const short* __restrict__ Vpk,  // packed B-frags
    float* __restrict__ out) {      // [B][S][D] fp32
    __shared__ short Ks0[8 * 512];                   // 8 KB: K tile (even)
    __shared__ short Ks1[8 * 512];                   // 8 KB: K tile (odd)
    __shared__ short Vs0[8 * 512];                   // 8 KB: V tile (even)
    __shared__ short Vs1[8 * 512];                   // 8 KB: V tile (odd)

    const int bid = blockIdx.x;
    const int gb = bid & 7;              // XCD selector = (b*4+g)
    const int rep = (bid >> 3) & 3;
    const int qt = bid >> 5;             // 0..31
    const int b = gb >> 2, g = gb & 3;
    const int h = rep * 4 + g;
    const int tid = threadIdx.x, w = tid >> 6, lane = tid & 63;
    const int quad = lane >> 4, l16 = lane & 15;

    // Q fragments: wave w owns rows qt*64 + w*32 + rg*16 + l16 (as B operand)
    bh8 qf[2][4];
#pragma unroll
    for (int rg = 0; rg < 2; ++rg) {
        int s = qt * 64 + w * 32 + rg * 16 + l16;
        const short* qp = Qb + (((size_t)(b * 16 + h) * 2048 + s) << 7);
#pragma unroll
        for (int ks = 0; ks < 4; ++ks)
            qf[rg][ks] = *(const bh8*)(qp + ks * 32 + quad * 8);
    }

    // frag geometry: K frags for 32-key tile kt contiguous at kt*4096
    // (frag idx = kt*8 + nti*4 + ks). V frags for tile kt: base
    // (kt>>1)*8192 + (kt&1)*512, stride 1024 shorts.
    const short* kbase = Kpk + ((size_t)gb * 32) * 8192;
    const short* vbase = Vpk + ((size_t)gb * 32) * 8192;

    // hoisted per-lane LDS read pointers (compile-time offsets thereafter)
    const short* pK0 = Ks0 + lane * 8;
    const short* pK1 = Ks1 + lane * 8;
    const short* pV0 = Vs0 + lane * 8;
    const short* pV1 = Vs1 + lane * 8;

    fx4 ctx[2][8];
#pragma unroll
    for (int rg = 0; rg < 2; ++rg)
#pragma unroll
        for (int j = 0; j < 8; ++j) ctx[rg][j] = fx4{0.f, 0.f, 0.f, 0.f};
    float l_part[2] = {0.f, 0.f};   // per-lane: q-row rg*16 + l16, this quad's keys

    // cross-tile pipeline state: paP = P(prev tile), vfA/vfB = V regs
    // (even/odd tiles). Zero-init paP+vfB makes the first PV a no-op.
    const bh8 z8 = bh8{0, 0, 0, 0, 0, 0, 0, 0};
    bh8 paP[2] = {z8, z8};
    bh8 vfA[8], vfB[8];
#pragma unroll
    for (int f = 0; f < 8; ++f) { vfA[f] = z8; vfB[f] = z8; }

// barrier with LDS-read drain: __syncthreads semantics minus the vmcnt drain.
// lgkmcnt(0) also guarantees the vf ds_reads have LANDED IN REGISTERS before
// the buffer they came from is overwritten by the next stage (R8 race fix).
#define AT_BARRIER()  asm volatile("s_waitcnt lgkmcnt(0)\n\ts_barrier" ::: "memory")
#define AT_VM(N)      asm volatile("s_waitcnt vmcnt(" #N ")" ::: "memory")

    // stage tile `kn` into statically-named dest buffers; wave w loads
    // K frags w*4..w*4+3 and V frags w*4..w*4+3 (8 gload_lds per wave)
#define AT_STAGE(KsD, VsD, kn)                                                  \
    do {                                                                        \
        const short* kp_ = kbase + (size_t)(kn) * 4096;                         \
        const short* vp_ = vbase + (size_t)((kn) >> 1) * 8192 + ((kn) & 1) * 512;\
        _Pragma("unroll")                                                       \
        for (int i = 0; i < 4; ++i) {                                           \
            int f = w * 4 + i;                                                  \
            __builtin_amdgcn_global_load_lds((GAu*)(kp_ + f * 512 + lane * 8),  \
                                             (LAu*)(KsD + f * 512), 16, 0, 0);  \
            __builtin_amdgcn_global_load_lds((GAu*)(vp_ + (size_t)f * 1024 + lane * 8),\
                                             (LAu*)(VsD + f * 512), 16, 0, 0);  \
        }                                                                       \
    } while (0)

    // phase t: load V(t)->vfC; QK(t) from Ks; PV(t-1) with paP x vfP (pure
    // register, independent of QK's results -> 32 contiguous MFMAs); then
    // softmax(t) -> paP in the MFMA pipe shadow.
#define AT_COMPUTE(pKC, pVC, vfC, vfP)                                          \
    do {                                                                        \
        _Pragma("unroll")                                                       \
        for (int nt = 0; nt < 8; ++nt)                                          \
            vfC[nt] = *(const bh8*)((pVC) + nt * 512);                          \
        fx4 sc[2][2];                                                           \
        sc[0][0] = fx4{0.f, 0.f, 0.f, 0.f}; sc[0][1] = fx4{0.f, 0.f, 0.f, 0.f}; \
        sc[1][0] = fx4{0.f, 0.f, 0.f, 0.f}; sc[1][1] = fx4{0.f, 0.f, 0.f, 0.f}; \
        __builtin_amdgcn_s_setprio(1);                                          \
        _Pragma("unroll")                                                       \
        for (int nti = 0; nti < 2; ++nti) {                                     \
            _Pragma("unroll")                                                   \
            for (int ks = 0; ks < 4; ++ks) {                                    \
                bh8 kf = *(const bh8*)((pKC) + (nti * 4 + ks) * 512);           \
                sc[0][nti] = __builtin_amdgcn_mfma_f32_16x16x32_bf16(kf, qf[0][ks], sc[0][nti], 0, 0, 0); \
                sc[1][nti] = __builtin_amdgcn_mfma_f32_16x16x32_bf16(kf, qf[1][ks], sc[1][nti], 0, 0, 0); \
            }                                                                   \
        }                                                                       \
        _Pragma("unroll")                                                       \
        for (int nt = 0; nt < 8; ++nt) {                                        \
            ctx[0][nt] = __builtin_amdgcn_mfma_f32_16x16x32_bf16(paP[0], vfP[nt], ctx[0][nt], 0, 0, 0); \
            ctx[1][nt] = __builtin_amdgcn_mfma_f32_16x16x32_bf16(paP[1], vfP[nt], ctx[1][nt], 0, 0, 0); \
        }                                                                       \
        __builtin_amdgcn_s_setprio(0);                                          \
        _Pragma("unroll")                                                       \
        for (int rg = 0; rg < 2; ++rg) {                                        \
            float e0 = __builtin_amdgcn_exp2f(sc[rg][0][0]);                    \
            float e1 = __builtin_amdgcn_exp2f(sc[rg][0][1]);                    \
            float e2 = __builtin_amdgcn_exp2f(sc[rg][0][2]);                    \
            float e3 = __builtin_amdgcn_exp2f(sc[rg][0][3]);                    \
            float e4 = __builtin_amdgcn_exp2f(sc[rg][1][0]);                    \
            float e5 = __builtin_amdgcn_exp2f(sc[rg][1][1]);                    \
            float e6 = __builtin_amdgcn_exp2f(sc[rg][1][2]);                    \
            float e7 = __builtin_amdgcn_exp2f(sc[rg][1][3]);                    \
            l_part[rg] += ((e0 + e1) + (e2 + e3)) + ((e4 + e5) + (e6 + e7));    \
            unsigned a[4];                                                      \
            a[0] = pk_bf16(e0, e1);                                             \
            a[1] = pk_bf16(e2, e3);                                             \
            a[2] = pk_bf16(e4, e5);                                             \
            a[3] = pk_bf16(e6, e7);                                             \
            paP[rg] = *(const bh8*)a;                                           \
        }                                                                       \
    } while (0)

    // ---- prologue: stage tiles 0 and 1; single exposed drain ----
    AT_STAGE(Ks0, Vs0, 0);
    AT_STAGE(Ks1, Vs1, 1);
    AT_VM(0);          // tiles 0,1 landed (this wave)
    AT_BARRIER();      // visible to both waves

    // steady state per body: enter with buf holding tile kt (landed) and
    // stage(kt+1) 8-outstanding (after first iter).
    for (int kt = 0; kt < 62; kt += 2) {
        AT_COMPUTE(pK0, pV0, vfA, vfB);  // tile kt: QK(kt) + PV(kt-1)
        AT_BARRIER();                    // all waves' buf0 reads landed in regs
        AT_STAGE(Ks0, Vs0, kt + 2);      // overwrite buf0 (in flight)
        AT_VM(8);                        // tile kt+1 landed (issued a full phase ago)
        AT_BARRIER();                    // tile kt+1 visible
        AT_COMPUTE(pK1, pV1, vfB, vfA);  // tile kt+1: QK(kt+1) + PV(kt)
        AT_BARRIER();                    // all waves' buf1 reads landed in regs
        AT_STAGE(Ks1, Vs1, kt + 3);      // overwrite buf1 (kt+3 <= 63)
        AT_VM(8);                        // tile kt+2 landed
        AT_BARRIER();                    // tile kt+2 visible
    }
    // ---- tail: tiles 62 (landed in buf0), 63 (8-outstanding into buf1) ----
    AT_COMPUTE(pK0, pV0, vfA, vfB);      // tile 62: QK(62) + PV(61)
    AT_VM(0);                            // tile 63 landed
    AT_BARRIER();                        // visible
    AT_COMPUTE(pK1, pV1, vfB, vfA);      // tile 63: QK(63) + PV(62)
    // final peeled PV(63): P(63) x V(63) (vfB holds tile 63's V)
#pragma unroll
    for (int nt = 0; nt < 8; ++nt) {
        ctx[0][nt] = __builtin_amdgcn_mfma_f32_16x16x32_bf16(paP[0], vfB[nt], ctx[0][nt], 0, 0, 0);
        ctx[1][nt] = __builtin_amdgcn_mfma_f32_16x16x32_bf16(paP[1], vfB[nt], ctx[1][nt], 0, 0, 0);
    }
#undef AT_STAGE
#undef AT_COMPUTE
#undef AT_BARRIER
#undef AT_VM

    // ---- epilogue ----
    // ctx[rg][nt][r]: q-row qt*64 + w*32 + rg*16 + quad*4 + r, hd nt*16+l16.
    // l_part[rg]: partial rowsum for q-row rg*16+l16 over this quad's keys;
    // full rowsum = reduce across quads (xor 16, 32), then broadcast.
#pragma unroll
    for (int rg = 0; rg < 2; ++rg) {
        float lsum = l_part[rg];
        lsum += __shfl_xor(lsum, 16);
        lsum += __shfl_xor(lsum, 32);   // now rowsum(rg*16 + l16), all quads
        int srow = qt * 64 + w * 32 + rg * 16 + quad * 4;
#pragma unroll
        for (int r = 0; r < 4; ++r) {
            float inv = 1.f / __shfl(lsum, quad * 4 + r);
            size_t rowoff = ((size_t)b * 2048 + (srow + r)) * 2048 + h * 128;
#pragma unroll
            for (int nt = 0; nt < 8; ++nt)
                out[rowoff + nt * 16 + l16] = ctx[rg][nt][r] * inv;
        }
    }
}

// ---------------- launcher ----------------
extern "C" void kernel_launch(void* const* d_in, const int* in_sizes, int n_in,
                              void* d_out, int out_size, void* d_ws, size_t ws_size,
                              hipStream_t stream) {
    const float* hs = (const float*)d_in[0];
    const float* Wq = (const float*)d_in[1];
    const float* bq = (const float*)d_in[2];
    const float* Wk = (const float*)d_in[3];
    const float* bk = (const float*)d_in[4];
    const float* Wv = (const float*)d_in[5];
    const float* bv = (const float*)d_in[6];
    float* out = (float*)d_out;

    char* ws = (char*)d_ws;
    short* Xbf = (short*)(ws);                       // 16 MiB
    short* WqT = (short*)(ws + 16777216);            // 8 MiB
    short* WkT = (short*)(ws + 25165824);            // 2 MiB
    short* WvT = (short*)(ws + 27262976);            // 2 MiB
    short* Qb  = (short*)(ws + 29360128);            // 16 MiB
    short* Kpk = (short*)(ws + 46137344);            // 4 MiB
    short* Vpk = (short*)(ws + 50331648);            // 4 MiB

    prep_all<<<9728, 256, 0, stream>>>(hs, Xbf, Wq, WqT, Wk, WkT, Wv, WvT);
    proj_gemm<<<dim3(32, 24), 256, 0, stream>>>(Xbf, WqT, WkT, WvT, bq, bk, bv,
                                                Qb, Kpk, Vpk);
    attn<<<1024, 128, 0, stream>>>(Qb, Kpk, Vpk, out);
}

// Round 15
// 249.582 us; speedup vs baseline: 1.0644x; 1.0337x over previous
//
#include <hip/hip_runtime.h>
#include <hip/hip_bf16.h>

// ---------------- problem constants ----------------
#define QSCALE   0.08838834764831845f               // 1/sqrt(128)
#define QKSCALE  0.1275174468755322f                // QSCALE * log2(e)

typedef __attribute__((ext_vector_type(8))) short bh8;   // 8 bf16 (4 VGPRs)
typedef __attribute__((ext_vector_type(4))) float fx4;   // 4 fp32
typedef __attribute__((ext_vector_type(4))) short sh4;

typedef const __attribute__((address_space(1))) unsigned GAu;
typedef __attribute__((address_space(3))) unsigned LAu;

__device__ __forceinline__ short f2bf(float f) {
    unsigned u = __float_as_uint(f);
    unsigned r = u + 0x7fffu + ((u >> 16) & 1u);   // RNE
    return (short)(r >> 16);
}

__device__ __forceinline__ unsigned pk_bf16(float x, float y) {
    union { __hip_bfloat162 h; unsigned u; } cv;
    cv.h = __float22bfloat162_rn(float2{x, y});    // x -> low short, y -> high short
    return cv.u;
}

// ---------------- fused prep v2: X cvt + 3 weight transposes, wide I/O (R13) ----------------
//   blocks [0,8192)     : cvt X fp32 -> bf16 (1 float4/thread)
//   blocks [8192,9216)  : transpose Wq [2048][2048] -> WqT (32x32 tiles of 64)
//   blocks [9216,9472)  : transpose Wk [2048][512]  -> WkT (8x32 tiles)
//   blocks [9472,9728)  : transpose Wv [2048][512]  -> WvT (8x32 tiles)
__global__ __launch_bounds__(256) void prep_all(
    const float* __restrict__ x,  short* __restrict__ xo,
    const float* __restrict__ wq, short* __restrict__ wqt,
    const float* __restrict__ wk, short* __restrict__ wkt,
    const float* __restrict__ wv, short* __restrict__ wvt) {
    __shared__ float tile[64][65];
    const int bid = blockIdx.x;
    const int tid = threadIdx.x;

    if (bid < 8192) {
        int i = bid * 256 + tid;
        float4 v = ((const float4*)x)[i];
        sh4 s;
        s.x = f2bf(v.x); s.y = f2bf(v.y); s.z = f2bf(v.z); s.w = f2bf(v.w);
        ((sh4*)xo)[i] = s;
        return;
    }

    const float* w; short* wt; int N, nb, kb;
    int t = bid - 8192;
    if (t < 1024)      { w = wq; wt = wqt; N = 2048; nb = t & 31; kb = t >> 5; }
    else if (t < 1280) { w = wk; wt = wkt; N = 512;  t -= 1024; nb = t & 7; kb = t >> 3; }
    else               { w = wv; wt = wvt; N = 512;  t -= 1280; nb = t & 7; kb = t >> 3; }
    const int K = 2048;

    // read: 64 rows (k) x 64 cols (n), float4 per thread x 4 passes
    {
        int c4 = tid & 15, r0 = tid >> 4;
#pragma unroll
        for (int rr = 0; rr < 4; ++rr) {
            int r = r0 + rr * 16;
            float4 v = *(const float4*)&w[(size_t)(kb * 64 + r) * N + nb * 64 + c4 * 4];
            *(float4*)&tile[r][c4 * 4] = v;
        }
    }
    __syncthreads();
    // write: WT row n gets k-run; short4 per thread x 4 passes
    {
        int k4 = tid & 15, n0 = tid >> 4;
#pragma unroll
        for (int rr = 0; rr < 4; ++rr) {
            int n = n0 + rr * 16;
            sh4 s;
            s.x = f2bf(tile[k4 * 4 + 0][n]);
            s.y = f2bf(tile[k4 * 4 + 1][n]);
            s.z = f2bf(tile[k4 * 4 + 2][n]);
            s.w = f2bf(tile[k4 * 4 + 3][n]);
            *(sh4*)&wt[(size_t)(nb * 64 + n) * K + kb * 64 + k4 * 4] = s;
        }
    }
}

// ---------------- fused QKV projection GEMM: BK=64, A-in-registers (R15) ----------------
// C[4096 x 3072]: n-tiles 0..15 -> Q, 16..19 -> K, 20..23 -> V
// R14 accounting: proj at 93us is issue-idle (~650cy work per ~3484cy round;
// HBM 12%, L2 24%, LDS ~50%, conflicts nil). The R4 phase (16 MFMA, ~300cy)
// is too short to hide the per-barrier vmcnt(0) drain, and R10 showed extra
// barriers regress. R15: (a) BK=64 -- 32 MFMA + 16 ds_reads per phase, 32
// barriers instead of 64, drain amortized over ~2x compute; (b) A-tile LDS
// round-trip REMOVED -- each wave's A-rows are wave-exclusive, so A frags
// load directly global->register (plain loads, compiler-managed vmcnt; X is
// L2/L3 resident). LDS = B-only [2 dbuf][2 ksub][128x32] = 32 KB exactly;
// per-FLOP LDS traffic -29%. launch_bounds(256,3) pins 3 waves/SIMD (acc=128
// + temps ~= 165 VGPR). Same B swizzle, epilogue, __syncthreads schedule.
// R7 Kpk packing (for swapped-QK attn): frag (b,g,kt32,nti,ks): key u = s&31
// maps to group nti=(u>>2)&1, frag row fl16=(u>>3)*4+(u&3); lane=qd*16+fl16,
// j<8 holds K[key][ks*32+qd*8+j]. Vpk unchanged.
__global__ __launch_bounds__(256, 3) void proj_gemm(
    const short* __restrict__ X,     // [4096][2048] bf16
    const short* __restrict__ WqT,   // [2048][2048] bf16 (N-major)
    const short* __restrict__ WkT,   // [512][2048]
    const short* __restrict__ WvT,   // [512][2048]
    const float* __restrict__ bq, const float* __restrict__ bk,
    const float* __restrict__ bv,
    short* __restrict__ Qb, short* __restrict__ Kpk, short* __restrict__ Vpk) {
    __shared__ short Bs0[2 * 128 * 32];   // tile even: [ksub][128][32]
    __shared__ short Bs1[2 * 128 * 32];   // tile odd

    const int tid = threadIdx.x;
    const int bm = blockIdx.x;      // 0..31
    const int ntg = blockIdx.y;     // 0..23

    const short* Wm; const float* bias; int col0, kind;
    if (ntg < 16)      { Wm = WqT; bias = bq; col0 = ntg * 128;        kind = 0; }
    else if (ntg < 20) { Wm = WkT; bias = bk; col0 = (ntg - 16) * 128; kind = 1; }
    else               { Wm = WvT; bias = bv; col0 = (ntg - 20) * 128; kind = 2; }

    const int w = tid >> 6, lane = tid & 63, quad = lane >> 4, l16 = lane & 15;

    fx4 acc[2][8];
#pragma unroll
    for (int i = 0; i < 2; ++i)
#pragma unroll
        for (int j = 0; j < 8; ++j) acc[i][j] = fx4{0.f, 0.f, 0.f, 0.f};

    // B staging source (unchanged swizzle): row col0+srow, chunk scol
    const int srow = w * 16 + (lane >> 2);
    const int scol = (((lane & 3) ^ ((lane >> 2) & 3)) * 8);
    const short* Bg = Wm + (size_t)(col0 + srow) * 2048 + scol;
    const int stoff = w * 512;      // per-wave LDS staging offset (shorts)

    // A direct-from-global: lane (quad,l16) holds A[row][k=quad*8..+7];
    // frag (mt,ks) of K-tile kt at Ap + mt*16*2048 + kt*64 + ks*32
    const short* Ap = X + (size_t)(bm * 128 + w * 32 + l16) * 2048 + quad * 8;

    // B read pointers (swizzled chunk), row nt*16+l16 at + nt*512
    const int fchunk = (quad ^ (l16 & 3)) * 8;
    const int boff  = l16 * 32 + fchunk;
    const short* pB00 = Bs0 + boff;          // tile even, ksub 0
    const short* pB01 = Bs0 + 4096 + boff;   // tile even, ksub 1
    const short* pB10 = Bs1 + boff;          // tile odd,  ksub 0
    const short* pB11 = Bs1 + 4096 + boff;   // tile odd,  ksub 1

#define PG_STAGE(BsD, ktile)                                                    \
    do {                                                                        \
        _Pragma("unroll")                                                       \
        for (int ks = 0; ks < 2; ++ks) {                                        \
            const int k0_ = (ktile) * 64 + ks * 32;                             \
            _Pragma("unroll")                                                   \
            for (int j = 0; j < 2; ++j) {                                       \
                __builtin_amdgcn_global_load_lds(                               \
                    (GAu*)(Bg + (size_t)(j * 64) * 2048 + k0_),                 \
                    (LAu*)(BsD + ks * 4096 + stoff + j * 2048), 16, 0, 0);      \
            }                                                                   \
        }                                                                       \
    } while (0)

    // compute one BK=64 tile: 4 A-frags from global + 16 B ds_reads + 32 MFMA
#define PG_COMPUTE(pBk0, pBk1, ktile)                                           \
    do {                                                                        \
        const size_t ko_ = (size_t)(ktile) * 64;                                \
        bh8 a00 = *(const bh8*)(Ap + ko_);                                      \
        bh8 a10 = *(const bh8*)(Ap + 32768 + ko_);                              \
        bh8 a01 = *(const bh8*)(Ap + ko_ + 32);                                 \
        bh8 a11 = *(const bh8*)(Ap + 32768 + ko_ + 32);                         \
        _Pragma("unroll")                                                       \
        for (int nt = 0; nt < 8; ++nt) {                                        \
            bh8 bf = *(const bh8*)((pBk0) + nt * 512);                          \
            acc[0][nt] = __builtin_amdgcn_mfma_f32_16x16x32_bf16(a00, bf, acc[0][nt], 0, 0, 0); \
            acc[1][nt] = __builtin_amdgcn_mfma_f32_16x16x32_bf16(a10, bf, acc[1][nt], 0, 0, 0); \
        }                                                                       \
        _Pragma("unroll")                                                       \
        for (int nt = 0; nt < 8; ++nt) {                                        \
            bh8 bf = *(const bh8*)((pBk1) + nt * 512);                          \
            acc[0][nt] = __builtin_amdgcn_mfma_f32_16x16x32_bf16(a01, bf, acc[0][nt], 0, 0, 0); \
            acc[1][nt] = __builtin_amdgcn_mfma_f32_16x16x32_bf16(a11, bf, acc[1][nt], 0, 0, 0); \
        }                                                                       \
    } while (0)

    // ---- prologue: stage B tile 0 into buffer 0 ----
    PG_STAGE(Bs0, 0);
    __syncthreads();   // one exposed drain, prologue only

    // 32 K-tiles of 64, unrolled x2 over static buffers
    for (int kt = 0; kt < 32; kt += 2) {
        // body A: stage odd tile kt+1 -> Bs1; compute even tile kt from Bs0
        PG_STAGE(Bs1, kt + 1);
        PG_COMPUTE(pB00, pB01, kt);
        __syncthreads();   // drains stage(kt+1); fences Bs0 reuse below

        // body B: stage even tile kt+2 -> Bs0; compute odd tile kt+1 from Bs1
        if (kt < 30) PG_STAGE(Bs0, kt + 2);
        PG_COMPUTE(pB10, pB11, kt + 1);
        __syncthreads();   // drains stage(kt+2); fences Bs1 reuse next iter
    }
#undef PG_STAGE
#undef PG_COMPUTE

    // epilogue: row = bm*128 + w*32 + mt*16 + quad*4 + r ; col = col0 + nt*16 + l16
#pragma unroll
    for (int mt = 0; mt < 2; ++mt) {
        int srow2 = bm * 128 + w * 32 + mt * 16 + quad * 4;
#pragma unroll
        for (int nt = 0; nt < 8; ++nt) {
            int c = col0 + nt * 16 + l16;
            float bval = bias[c];
#pragma unroll
            for (int r = 0; r < 4; ++r) {
                int sg = srow2 + r;
                int b = sg >> 11, s = sg & 2047;
                float v = acc[mt][nt][r] + bval;
                int hd = c & 127;
                if (kind == 0) {
                    v *= QKSCALE;  // fold 1/sqrt(d)*log2(e) into Q
                    int h = c >> 7;
                    Qb[(((size_t)(b * 16 + h) * 2048 + s) << 7) + hd] = f2bf(v);
                } else if (kind == 1) {
                    // R7 interleaved packing for swapped-QK (see attn)
                    int g = c >> 7;
                    int kt32 = s >> 5, u = s & 31;
                    int nti = (u >> 2) & 1, fl16 = (u >> 3) * 4 + (u & 3);
                    int ks = hd >> 5, qd = (hd >> 3) & 3, j = hd & 7;
                    size_t frag = (((size_t)(b * 4 + g) * 64 + kt32) * 8 + nti * 4 + ks);
                    Kpk[frag * 512 + (qd * 16 + fl16) * 8 + j] = f2bf(v);
                } else {
                    int g = c >> 7;
                    int ktt = s >> 6, tl = s & 63;
                    int ts = tl >> 5, qd = (tl >> 3) & 3, j = tl & 7;
                    int fnt = hd >> 4, fl16 = hd & 15;
                    size_t frag = (((size_t)(b * 4 + g) * 32 + ktt) * 16 + fnt * 2 + ts);
                    Vpk[frag * 512 + (qd * 16 + fl16) * 8 + j] = f2bf(v);
                }
            }
        }
    }
}

// ---------------- flash attention: cross-tile PV pipeline (R14, validated) ----------------
// Counted-vmcnt schedule (R9): barriers = `s_waitcnt lgkmcnt(0); s_barrier`,
// counted vmcnt(8), two vmcnt(0) total. Swapped QK^T (R7): P lands lane-exact
// as the PV A-fragment. Cross-tile PV (R14): phase t computes PV(t-1) from
// registers so QK(t)+PV(t-1) = 32 back-to-back MFMAs and softmax(t) issues
// in the MFMA shadow. 1024 blocks; 128 threads; LDS = 32768 B.
__global__ __launch_bounds__(128, 2) void attn(
    const short* __restrict__ Qb,   // [B][HQ][S][128] bf16, pre-scaled by QKSCALE
    const short* __restrict__ Kpk,  // packed A-frags (interleaved keys)
    const short* __restrict__ Vpk,  // packed B-frags
    float* __restrict__ out) {      // [B][S][D] fp32
    __shared__ short Ks0[8 * 512];                   // 8 KB: K tile (even)
    __shared__ short Ks1[8 * 512];                   // 8 KB: K tile (odd)
    __shared__ short Vs0[8 * 512];                   // 8 KB: V tile (even)
    __shared__ short Vs1[8 * 512];                   // 8 KB: V tile (odd)

    const int bid = blockIdx.x;
    const int gb = bid & 7;              // XCD selector = (b*4+g)
    const int rep = (bid >> 3) & 3;
    const int qt = bid >> 5;             // 0..31
    const int b = gb >> 2, g = gb & 3;
    const int h = rep * 4 + g;
    const int tid = threadIdx.x, w = tid >> 6, lane = tid & 63;
    const int quad = lane >> 4, l16 = lane & 15;

    // Q fragments: wave w owns rows qt*64 + w*32 + rg*16 + l16 (as B operand)
    bh8 qf[2][4];
#pragma unroll
    for (int rg = 0; rg < 2; ++rg) {
        int s = qt * 64 + w * 32 + rg * 16 + l16;
        const short* qp = Qb + (((size_t)(b * 16 + h) * 2048 + s) << 7);
#pragma unroll
        for (int ks = 0; ks < 4; ++ks)
            qf[rg][ks] = *(const bh8*)(qp + ks * 32 + quad * 8);
    }

    // frag geometry: K frags for 32-key tile kt contiguous at kt*4096
    // (frag idx = kt*8 + nti*4 + ks). V frags for tile kt: base
    // (kt>>1)*8192 + (kt&1)*512, stride 1024 shorts.
    const short* kbase = Kpk + ((size_t)gb * 32) * 8192;
    const short* vbase = Vpk + ((size_t)gb * 32) * 8192;

    // hoisted per-lane LDS read pointers (compile-time offsets thereafter)
    const short* pK0 = Ks0 + lane * 8;
    const short* pK1 = Ks1 + lane * 8;
    const short* pV0 = Vs0 + lane * 8;
    const short* pV1 = Vs1 + lane * 8;

    fx4 ctx[2][8];
#pragma unroll
    for (int rg = 0; rg < 2; ++rg)
#pragma unroll
        for (int j = 0; j < 8; ++j) ctx[rg][j] = fx4{0.f, 0.f, 0.f, 0.f};
    float l_part[2] = {0.f, 0.f};   // per-lane: q-row rg*16 + l16, this quad's keys

    // cross-tile pipeline state: paP = P(prev tile), vfA/vfB = V regs
    // (even/odd tiles). Zero-init paP+vfB makes the first PV a no-op.
    const bh8 z8 = bh8{0, 0, 0, 0, 0, 0, 0, 0};
    bh8 paP[2] = {z8, z8};
    bh8 vfA[8], vfB[8];
#pragma unroll
    for (int f = 0; f < 8; ++f) { vfA[f] = z8; vfB[f] = z8; }

// barrier with LDS-read drain: __syncthreads semantics minus the vmcnt drain.
// lgkmcnt(0) also guarantees the vf ds_reads have LANDED IN REGISTERS before
// the buffer they came from is overwritten by the next stage (R8 race fix).
#define AT_BARRIER()  asm volatile("s_waitcnt lgkmcnt(0)\n\ts_barrier" ::: "memory")
#define AT_VM(N)      asm volatile("s_waitcnt vmcnt(" #N ")" ::: "memory")

    // stage tile `kn` into statically-named dest buffers; wave w loads
    // K frags w*4..w*4+3 and V frags w*4..w*4+3 (8 gload_lds per wave)
#define AT_STAGE(KsD, VsD, kn)                                                  \
    do {                                                                        \
        const short* kp_ = kbase + (size_t)(kn) * 4096;                         \
        const short* vp_ = vbase + (size_t)((kn) >> 1) * 8192 + ((kn) & 1) * 512;\
        _Pragma("unroll")                                                       \
        for (int i = 0; i < 4; ++i) {                                           \
            int f = w * 4 + i;                                                  \
            __builtin_amdgcn_global_load_lds((GAu*)(kp_ + f * 512 + lane * 8),  \
                                             (LAu*)(KsD + f * 512), 16, 0, 0);  \
            __builtin_amdgcn_global_load_lds((GAu*)(vp_ + (size_t)f * 1024 + lane * 8),\
                                             (LAu*)(VsD + f * 512), 16, 0, 0);  \
        }                                                                       \
    } while (0)

    // phase t: load V(t)->vfC; QK(t) from Ks; PV(t-1) with paP x vfP (pure
    // register, independent of QK's results -> 32 contiguous MFMAs); then
    // softmax(t) -> paP in the MFMA pipe shadow.
#define AT_COMPUTE(pKC, pVC, vfC, vfP)                                          \
    do {                                                                        \
        _Pragma("unroll")                                                       \
        for (int nt = 0; nt < 8; ++nt)                                          \
            vfC[nt] = *(const bh8*)((pVC) + nt * 512);                          \
        fx4 sc[2][2];                                                           \
        sc[0][0] = fx4{0.f, 0.f, 0.f, 0.f}; sc[0][1] = fx4{0.f, 0.f, 0.f, 0.f}; \
        sc[1][0] = fx4{0.f, 0.f, 0.f, 0.f}; sc[1][1] = fx4{0.f, 0.f, 0.f, 0.f}; \
        __builtin_amdgcn_s_setprio(1);                                          \
        _Pragma("unroll")                                                       \
        for (int nti = 0; nti < 2; ++nti) {                                     \
            _Pragma("unroll")                                                   \
            for (int ks = 0; ks < 4; ++ks) {                                    \
                bh8 kf = *(const bh8*)((pKC) + (nti * 4 + ks) * 512);           \
                sc[0][nti] = __builtin_amdgcn_mfma_f32_16x16x32_bf16(kf, qf[0][ks], sc[0][nti], 0, 0, 0); \
                sc[1][nti] = __builtin_amdgcn_mfma_f32_16x16x32_bf16(kf, qf[1][ks], sc[1][nti], 0, 0, 0); \
            }                                                                   \
        }                                                                       \
        _Pragma("unroll")                                                       \
        for (int nt = 0; nt < 8; ++nt) {                                        \
            ctx[0][nt] = __builtin_amdgcn_mfma_f32_16x16x32_bf16(paP[0], vfP[nt], ctx[0][nt], 0, 0, 0); \
            ctx[1][nt] = __builtin_amdgcn_mfma_f32_16x16x32_bf16(paP[1], vfP[nt], ctx[1][nt], 0, 0, 0); \
        }                                                                       \
        __builtin_amdgcn_s_setprio(0);                                          \
        _Pragma("unroll")                                                       \
        for (int rg = 0; rg < 2; ++rg) {                                        \
            float e0 = __builtin_amdgcn_exp2f(sc[rg][0][0]);                    \
            float e1 = __builtin_amdgcn_exp2f(sc[rg][0][1]);                    \
            float e2 = __builtin_amdgcn_exp2f(sc[rg][0][2]);                    \
            float e3 = __builtin_amdgcn_exp2f(sc[rg][0][3]);                    \
            float e4 = __builtin_amdgcn_exp2f(sc[rg][1][0]);                    \
            float e5 = __builtin_amdgcn_exp2f(sc[rg][1][1]);                    \
            float e6 = __builtin_amdgcn_exp2f(sc[rg][1][2]);                    \
            float e7 = __builtin_amdgcn_exp2f(sc[rg][1][3]);                    \
            l_part[rg] += ((e0 + e1) + (e2 + e3)) + ((e4 + e5) + (e6 + e7));    \
            unsigned a[4];                                                      \
            a[0] = pk_bf16(e0, e1);                                             \
            a[1] = pk_bf16(e2, e3);                                             \
            a[2] = pk_bf16(e4, e5);                                             \
            a[3] = pk_bf16(e6, e7);                                             \
            paP[rg] = *(const bh8*)a;                                           \
        }                                                                       \
    } while (0)

    // ---- prologue: stage tiles 0 and 1; single exposed drain ----
    AT_STAGE(Ks0, Vs0, 0);
    AT_STAGE(Ks1, Vs1, 1);
    AT_VM(0);          // tiles 0,1 landed (this wave)
    AT_BARRIER();      // visible to both waves

    // steady state per body: enter with buf holding tile kt (landed) and
    // stage(kt+1) 8-outstanding (after first iter).
    for (int kt = 0; kt < 62; kt += 2) {
        AT_COMPUTE(pK0, pV0, vfA, vfB);  // tile kt: QK(kt) + PV(kt-1)
        AT_BARRIER();                    // all waves' buf0 reads landed in regs
        AT_STAGE(Ks0, Vs0, kt + 2);      // overwrite buf0 (in flight)
        AT_VM(8);                        // tile kt+1 landed (issued a full phase ago)
        AT_BARRIER();                    // tile kt+1 visible
        AT_COMPUTE(pK1, pV1, vfB, vfA);  // tile kt+1: QK(kt+1) + PV(kt)
        AT_BARRIER();                    // all waves' buf1 reads landed in regs
        AT_STAGE(Ks1, Vs1, kt + 3);      // overwrite buf1 (kt+3 <= 63)
        AT_VM(8);                        // tile kt+2 landed
        AT_BARRIER();                    // tile kt+2 visible
    }
    // ---- tail: tiles 62 (landed in buf0), 63 (8-outstanding into buf1) ----
    AT_COMPUTE(pK0, pV0, vfA, vfB);      // tile 62: QK(62) + PV(61)
    AT_VM(0);                            // tile 63 landed
    AT_BARRIER();                        // visible
    AT_COMPUTE(pK1, pV1, vfB, vfA);      // tile 63: QK(63) + PV(62)
    // final peeled PV(63): P(63) x V(63) (vfB holds tile 63's V)
#pragma unroll
    for (int nt = 0; nt < 8; ++nt) {
        ctx[0][nt] = __builtin_amdgcn_mfma_f32_16x16x32_bf16(paP[0], vfB[nt], ctx[0][nt], 0, 0, 0);
        ctx[1][nt] = __builtin_amdgcn_mfma_f32_16x16x32_bf16(paP[1], vfB[nt], ctx[1][nt], 0, 0, 0);
    }
#undef AT_STAGE
#undef AT_COMPUTE
#undef AT_BARRIER
#undef AT_VM

    // ---- epilogue ----
    // ctx[rg][nt][r]: q-row qt*64 + w*32 + rg*16 + quad*4 + r, hd nt*16+l16.
    // l_part[rg]: partial rowsum for q-row rg*16+l16 over this quad's keys;
    // full rowsum = reduce across quads (xor 16, 32), then broadcast.
#pragma unroll
    for (int rg = 0; rg < 2; ++rg) {
        float lsum = l_part[rg];
        lsum += __shfl_xor(lsum, 16);
        lsum += __shfl_xor(lsum, 32);   // now rowsum(rg*16 + l16), all quads
        int srow = qt * 64 + w * 32 + rg * 16 + quad * 4;
#pragma unroll
        for (int r = 0; r < 4; ++r) {
            float inv = 1.f / __shfl(lsum, quad * 4 + r);
            size_t rowoff = ((size_t)b * 2048 + (srow + r)) * 2048 + h * 128;
#pragma unroll
            for (int nt = 0; nt < 8; ++nt)
                out[rowoff + nt * 16 + l16] = ctx[rg][nt][r] * inv;
        }
    }
}

// ---------------- launcher ----------------
extern "C" void kernel_launch(void* const* d_in, const int* in_sizes, int n_in,
                              void* d_out, int out_size, void* d_ws, size_t ws_size,
                              hipStream_t stream) {
    const float* hs = (const float*)d_in[0];
    const float* Wq = (const float*)d_in[1];
    const float* bq = (const float*)d_in[2];
    const float* Wk = (const float*)d_in[3];
    const float* bk = (const float*)d_in[4];
    const float* Wv = (const float*)d_in[5];
    const float* bv = (const float*)d_in[6];
    float* out = (float*)d_out;

    char* ws = (char*)d_ws;
    short* Xbf = (short*)(ws);                       // 16 MiB
    short* WqT = (short*)(ws + 16777216);            // 8 MiB
    short* WkT = (short*)(ws + 25165824);            // 2 MiB
    short* WvT = (short*)(ws + 27262976);            // 2 MiB
    short* Qb  = (short*)(ws + 29360128);            // 16 MiB
    short* Kpk = (short*)(ws + 46137344);            // 4 MiB
    short* Vpk = (short*)(ws + 50331648);            // 4 MiB

    prep_all<<<9728, 256, 0, stream>>>(hs, Xbf, Wq, WqT, Wk, WkT, Wv, WvT);
    proj_gemm<<<dim3(32, 24), 256, 0, stream>>>(Xbf, WqT, WkT, WvT, bq, bk, bv,
                                                Qb, Kpk, Vpk);
    attn<<<1024, 128, 0, stream>>>(Qb, Kpk, Vpk, out);
}